// Round 8
// baseline (315.552 us; speedup 1.0000x reference)
//
#include <hip/hip_runtime.h>

#define IN_C 128
#define HID_C 64
#define OUT_C 32
#define NBLK 512    // edge blocks for bucket partition
#define NBUCK 512   // buckets = node>>8 (391 used for n=100000)
#define CAP 5120    // fixed bucket capacity: mean 4096 + 16 sigma

typedef unsigned int uint;
typedef unsigned short ushort;
typedef __attribute__((ext_vector_type(8))) short bf16x8;
typedef __attribute__((ext_vector_type(4))) float f32x4;

__device__ __forceinline__ uint bf16pair(float a, float b) {
  uint ua = __float_as_uint(a), ub = __float_as_uint(b);
  ua = (ua + 0x7FFFu + ((ua >> 16) & 1u)) >> 16;
  ub = (ub + 0x7FFFu + ((ub >> 16) & 1u)) >> 16;
  return ua | (ub << 16);
}

__device__ __forceinline__ uint bf16one(float a) {
  uint u = __float_as_uint(a);
  return (u + 0x7FFFu + ((u >> 16) & 1u)) >> 16;
}

// ---------- CSR build ----------

__global__ void __launch_bounds__(256) scatter_reserve_kernel(
    const int* __restrict__ row, const int* __restrict__ col,
    int* __restrict__ gcur, int* __restrict__ ebuf, int e, int epb) {
  __shared__ int hist[NBUCK];
  __shared__ int cur[NBUCK];
  int t = threadIdx.x, b = blockIdx.x;
  for (int i = t; i < NBUCK; i += 256) hist[i] = 0;
  __syncthreads();
  int s = b * epb, en = min(e, s + epb);
  for (int i = s + t; i < en; i += 256) atomicAdd(&hist[col[i] >> 8], 1);
  __syncthreads();
  for (int i = t; i < NBUCK; i += 256) {
    int h = hist[i];
    int base = h ? atomicAdd(&gcur[i], h) : 0;
    cur[i] = CAP * i + base;
  }
  __syncthreads();
  for (int i = s + t; i < en; i += 256) {
    int c = col[i], r = row[i];
    int bk = c >> 8;
    int p = atomicAdd(&cur[bk], 1);
    if (p < CAP * bk + CAP) ebuf[p] = r | ((c & 255) << 17);  // n < 2^17
  }
}

__global__ void __launch_bounds__(256) csr_kernel(const int* __restrict__ ebuf,
                                                  const int* __restrict__ gcur,
                                                  int* __restrict__ offS, int* __restrict__ offE,
                                                  int* __restrict__ srt, float* __restrict__ dinv,
                                                  int n) {
  __shared__ int cnt[256];
  __shared__ int base[256];
  int t = threadIdx.x, b = blockIdx.x;
  int es = b * CAP;
  int ec = min(gcur[b], CAP);
  cnt[t] = 0;
  __syncthreads();
  for (int i = t; i < ec; i += 256) atomicAdd(&cnt[(ebuf[es + i] >> 17) & 255], 1);
  __syncthreads();
  int v = cnt[t];
  base[t] = v;
  __syncthreads();
  for (int d = 1; d < 256; d <<= 1) {
    int a = (t >= d) ? base[t - d] : 0;
    __syncthreads();
    base[t] += a;
    __syncthreads();
  }
  int gstart = es + base[t] - v;
  int node = b * 256 + t;
  if (node < n) {
    offS[node] = gstart;
    offE[node] = gstart + v;
    dinv[node] = rsqrtf((float)(v + 1));
  }
  base[t] = gstart;  // repurpose as cursor
  __syncthreads();
  for (int i = t; i < ec; i += 256) {
    int pv = ebuf[es + i];
    int pos = atomicAdd(&base[(pv >> 17) & 255], 1);
    srt[pos] = pv & 0x1FFFF;
  }
}

// ---------- weight prep (bf16 hi/lo splits, transposed) ----------

__global__ void __launch_bounds__(256) prep_w_kernel(const float* __restrict__ W1,
                                                     const float* __restrict__ W2,
                                                     ushort* __restrict__ w1t_hi,
                                                     ushort* __restrict__ w1t_lo,
                                                     ushort* __restrict__ w2t_hi,
                                                     ushort* __restrict__ w2t_lo) {
  int t = threadIdx.x;
  for (int i = t; i < HID_C * IN_C; i += 256) {
    int c = i >> 7, k = i & 127;
    float v = W1[k * HID_C + c];
    uint h = bf16one(v);
    float lo = v - __uint_as_float(h << 16);
    w1t_hi[i] = (ushort)h;
    w1t_lo[i] = (ushort)bf16one(lo);
  }
  for (int i = t; i < OUT_C * HID_C; i += 256) {
    int c = i >> 6, k = i & 63;
    float v = W2[k * OUT_C + c];
    uint h = bf16one(v);
    float lo = v - __uint_as_float(h << 16);
    w2t_hi[i] = (ushort)h;
    w2t_lo[i] = (ushort)bf16one(lo);
  }
}

// ---------- gemm1 via split-bf16 MFMA -> quarter planes ----------
// xw1q[q][r][16] = bf16((x[r,:] @ W1)[:,q*16..] * dinv[r]).  64 rows/block.
#define APAD 136
__global__ void __launch_bounds__(256) gemm1_mfma_kernel(
    const float* __restrict__ x, const ushort* __restrict__ w1t_hi,
    const ushort* __restrict__ w1t_lo, const float* __restrict__ dinv,
    ushort* __restrict__ xw1q, int n, int planeN) {
  __shared__ ushort xs_hi[64 * APAD];
  __shared__ ushort xs_lo[64 * APAD];
  __shared__ float dinv_s[64];
  int t = threadIdx.x;
  int row0 = blockIdx.x * 64;
  if (t < 64) {
    int rr = row0 + t;
    dinv_s[t] = rr < n ? dinv[rr] : 0.f;
  }
  for (int task = t; task < 64 * 16; task += 256) {
    int r = task >> 4, kc = task & 15;
    int grow = row0 + r;
    uint4 hq = {0u, 0u, 0u, 0u}, lq = {0u, 0u, 0u, 0u};
    if (grow < n) {
      const float* xp = x + (size_t)grow * IN_C + kc * 8;
      float4 v0 = *(const float4*)xp;
      float4 v1 = *(const float4*)(xp + 4);
      float vv[8] = {v0.x, v0.y, v0.z, v0.w, v1.x, v1.y, v1.z, v1.w};
      uint hu[8];
      float lf[8];
#pragma unroll
      for (int i = 0; i < 8; ++i) {
        hu[i] = bf16one(vv[i]);
        lf[i] = vv[i] - __uint_as_float(hu[i] << 16);
      }
      hq = make_uint4(hu[0] | (hu[1] << 16), hu[2] | (hu[3] << 16),
                      hu[4] | (hu[5] << 16), hu[6] | (hu[7] << 16));
      lq = make_uint4(bf16pair(lf[0], lf[1]), bf16pair(lf[2], lf[3]),
                      bf16pair(lf[4], lf[5]), bf16pair(lf[6], lf[7]));
    }
    *(uint4*)(xs_hi + r * APAD + kc * 8) = hq;
    *(uint4*)(xs_lo + r * APAD + kc * 8) = lq;
  }
  __syncthreads();
  int wv = t >> 6, lane = t & 63, m = lane & 15, q = lane >> 4;
  f32x4 acc[4];
#pragma unroll
  for (int ct = 0; ct < 4; ++ct) acc[ct] = (f32x4){0.f, 0.f, 0.f, 0.f};
  const ushort* ah_p = xs_hi + (wv * 16 + m) * APAD + q * 8;
  const ushort* al_p = xs_lo + (wv * 16 + m) * APAD + q * 8;
#pragma unroll
  for (int kb = 0; kb < 4; ++kb) {
    bf16x8 ah = *(const bf16x8*)(ah_p + kb * 32);
    bf16x8 al = *(const bf16x8*)(al_p + kb * 32);
#pragma unroll
    for (int ct = 0; ct < 4; ++ct) {
      const ushort* bp = w1t_hi + (ct * 16 + m) * IN_C + kb * 32 + q * 8;
      bf16x8 bh = *(const bf16x8*)bp;
      bf16x8 bl = *(const bf16x8*)(bp + (size_t)(w1t_lo - w1t_hi));
      acc[ct] = __builtin_amdgcn_mfma_f32_16x16x32_bf16(ah, bh, acc[ct], 0, 0, 0);
      acc[ct] = __builtin_amdgcn_mfma_f32_16x16x32_bf16(al, bh, acc[ct], 0, 0, 0);
      acc[ct] = __builtin_amdgcn_mfma_f32_16x16x32_bf16(ah, bl, acc[ct], 0, 0, 0);
    }
  }
#pragma unroll
  for (int ct = 0; ct < 4; ++ct) {
#pragma unroll
    for (int rg = 0; rg < 4; ++rg) {
      int lr = wv * 16 + q * 4 + rg;
      int grow = row0 + lr;
      if (grow < n)
        xw1q[(size_t)ct * planeN + (size_t)grow * 16 + m] =
            (ushort)bf16one(acc[ct][rg] * dinv_s[lr]);
    }
  }
}

// ---------- plane gathers ----------

// gather1: blockIdx -> (quarter = bid&3, chunk). 32 nodes/block, 8-lane group
// per node, lane = 1 dword (2 bf16 feats) of the 32 B quarter row.
__global__ void __launch_bounds__(256) gather1_plane_kernel(
    const int* __restrict__ offS, const int* __restrict__ offE, const int* __restrict__ srt,
    const float* __restrict__ dinv, const ushort* __restrict__ xw1q,
    const float* __restrict__ b1, ushort* __restrict__ hb, int n, int planeN) {
  int t = threadIdx.x, bid = blockIdx.x;
  int pq = bid & 3, chunk = bid >> 2;
  int g = t >> 3, fl = t & 7, lane = t & 63;
  int c = chunk * 32 + g;
  if (c >= n) return;
  const uint* tbl = (const uint*)(xw1q + (size_t)pq * planeN);
  int js = offS[c], je = offE[c];
  float aL[4] = {0.f, 0.f, 0.f, 0.f}, aH[4] = {0.f, 0.f, 0.f, 0.f};
  for (int j = js; j < je; j += 8) {
    int idx = __builtin_nontemporal_load(srt + min(j + fl, je - 1));
#pragma unroll
    for (int k = 0; k < 8; ++k) {
      int r = __shfl(idx, (lane & 56) | k, 64);
      if (j + k < je) {
        uint w = tbl[(size_t)r * 8 + fl];
        aL[k & 3] += __uint_as_float(w << 16);
        aH[k & 3] += __uint_as_float(w & 0xFFFF0000u);
      }
    }
  }
  uint ws = tbl[(size_t)c * 8 + fl];  // self loop
  aL[0] += __uint_as_float(ws << 16);
  aH[0] += __uint_as_float(ws & 0xFFFF0000u);
  float dv = dinv[c];
  float2 bb = ((const float2*)b1)[pq * 8 + fl];
  float h0 = ((aL[0] + aL[1]) + (aL[2] + aL[3])) * dv + bb.x;
  float h1 = ((aH[0] + aH[1]) + (aH[2] + aH[3])) * dv + bb.y;
  h0 = h0 > 0.f ? h0 : 0.f;
  h1 = h1 > 0.f ? h1 : 0.f;
  ((uint*)hb)[(size_t)c * 32 + pq * 8 + fl] = bf16pair(h0, h1);
}

// gemm2 via MFMA: hw2h[h][r][16] = bf16((hb[r,:] @ W2)[:,h*16..] * dinv[r]).
// 64 rows/block, 4 waves; A (bf16, exact) direct from global, B split hi/lo.
__global__ void __launch_bounds__(256) gemm2_mfma_kernel(
    const ushort* __restrict__ hb, const ushort* __restrict__ w2t_hi,
    const ushort* __restrict__ w2t_lo, const float* __restrict__ dinv,
    ushort* __restrict__ hw2h, int n, int planeN) {
  int t = threadIdx.x;
  int wv = t >> 6, lane = t & 63, m = lane & 15, q = lane >> 4;
  int row0 = blockIdx.x * 64 + wv * 16;
  int arow = min(row0 + m, n - 1);
  const ushort* ap = hb + (size_t)arow * HID_C + q * 8;
  bf16x8 a0 = *(const bf16x8*)ap;
  bf16x8 a1 = *(const bf16x8*)(ap + 32);
  f32x4 acc[2];
  acc[0] = (f32x4){0.f, 0.f, 0.f, 0.f};
  acc[1] = (f32x4){0.f, 0.f, 0.f, 0.f};
#pragma unroll
  for (int ct = 0; ct < 2; ++ct) {
    const ushort* bp = w2t_hi + (ct * 16 + m) * HID_C + q * 8;
    const ushort* blp = w2t_lo + (ct * 16 + m) * HID_C + q * 8;
    bf16x8 bh0 = *(const bf16x8*)bp;
    bf16x8 bh1 = *(const bf16x8*)(bp + 32);
    bf16x8 bl0 = *(const bf16x8*)blp;
    bf16x8 bl1 = *(const bf16x8*)(blp + 32);
    acc[ct] = __builtin_amdgcn_mfma_f32_16x16x32_bf16(a0, bh0, acc[ct], 0, 0, 0);
    acc[ct] = __builtin_amdgcn_mfma_f32_16x16x32_bf16(a1, bh1, acc[ct], 0, 0, 0);
    acc[ct] = __builtin_amdgcn_mfma_f32_16x16x32_bf16(a0, bl0, acc[ct], 0, 0, 0);
    acc[ct] = __builtin_amdgcn_mfma_f32_16x16x32_bf16(a1, bl1, acc[ct], 0, 0, 0);
  }
#pragma unroll
  for (int ct = 0; ct < 2; ++ct) {
#pragma unroll
    for (int rg = 0; rg < 4; ++rg) {
      int node = row0 + q * 4 + rg;
      if (node < n)
        hw2h[(size_t)ct * planeN + (size_t)node * 16 + m] =
            (ushort)bf16one(acc[ct][rg] * dinv[node]);
    }
  }
}

// gather2: blockIdx -> (half = bid&1, chunk). 32 nodes/block, 8-lane group,
// lane = 1 dword (2 bf16 feats) of the 32 B half row. Writes final f32 out.
__global__ void __launch_bounds__(256) gather2_plane_kernel(
    const int* __restrict__ offS, const int* __restrict__ offE, const int* __restrict__ srt,
    const float* __restrict__ dinv, const ushort* __restrict__ hw2h,
    const float* __restrict__ b2, float* __restrict__ out, int n, int planeN) {
  int t = threadIdx.x, bid = blockIdx.x;
  int ph = bid & 1, chunk = bid >> 1;
  int g = t >> 3, fl = t & 7, lane = t & 63;
  int c = chunk * 32 + g;
  if (c >= n) return;
  const uint* tbl = (const uint*)(hw2h + (size_t)ph * planeN);
  int js = offS[c], je = offE[c];
  float aL[4] = {0.f, 0.f, 0.f, 0.f}, aH[4] = {0.f, 0.f, 0.f, 0.f};
  for (int j = js; j < je; j += 8) {
    int idx = __builtin_nontemporal_load(srt + min(j + fl, je - 1));
#pragma unroll
    for (int k = 0; k < 8; ++k) {
      int r = __shfl(idx, (lane & 56) | k, 64);
      if (j + k < je) {
        uint w = tbl[(size_t)r * 8 + fl];
        aL[k & 3] += __uint_as_float(w << 16);
        aH[k & 3] += __uint_as_float(w & 0xFFFF0000u);
      }
    }
  }
  uint ws = tbl[(size_t)c * 8 + fl];  // self loop
  aL[0] += __uint_as_float(ws << 16);
  aH[0] += __uint_as_float(ws & 0xFFFF0000u);
  float dv = dinv[c];
  float2 bb = ((const float2*)b2)[ph * 8 + fl];
  float2 o2;
  o2.x = ((aL[0] + aL[1]) + (aL[2] + aL[3])) * dv + bb.x;
  o2.y = ((aH[0] + aH[1]) + (aH[2] + aH[3])) * dv + bb.y;
  ((float2*)out)[(size_t)c * 16 + ph * 8 + fl] = o2;
}

extern "C" void kernel_launch(void* const* d_in, const int* in_sizes, int n_in,
                              void* d_out, int out_size, void* d_ws, size_t ws_size,
                              hipStream_t stream) {
  const float* x  = (const float*)d_in[0];
  const int*   ei = (const int*)d_in[1];
  const float* W1 = (const float*)d_in[2];
  const float* b1 = (const float*)d_in[3];
  const float* W2 = (const float*)d_in[4];
  const float* b2 = (const float*)d_in[5];
  float* out = (float*)d_out;

  int n = in_sizes[0] / IN_C;  // 100000
  int e = in_sizes[1] / 2;     // 1600000
  const int* row = ei;         // sources
  const int* col = ei + e;     // targets
  int planeN = n * 16;         // bf16 elems per feature plane

  // workspace (ebuf aliases xw1q — ebuf dead before gemm1 runs, stream-ordered)
  float* dinv = (float*)d_ws;                          // n
  int*   offS = (int*)(dinv + n);                      // n
  int*   offE = offS + n;                              // n
  int*   gcur = offE + n;                              // NBUCK
  int*   srt  = gcur + NBUCK;                          // NBUCK*CAP
  ushort* xw1q = (ushort*)(srt + (size_t)NBUCK * CAP); // 4 planes x n*16
  int*   ebuf = (int*)xw1q;                            // NBUCK*CAP ints (10.5MB <= 12.8MB)
  ushort* hb   = xw1q + (size_t)n * HID_C;             // n*64
  ushort* hw2h = hb + (size_t)n * HID_C;               // 2 planes x n*16
  ushort* w1t_hi = hw2h + (size_t)n * OUT_C;           // 64*128
  ushort* w1t_lo = w1t_hi + HID_C * IN_C;              // 64*128
  ushort* w2t_hi = w1t_lo + HID_C * IN_C;              // 32*64
  ushort* w2t_lo = w2t_hi + OUT_C * HID_C;             // 32*64

  int epb = (e + NBLK - 1) / NBLK;                     // 3125
  int nbuckets = (n + 255) / 256;                      // 391
  int chunks = (n + 31) / 32;                          // 3125

  hipMemsetAsync(gcur, 0, NBUCK * sizeof(int), stream);
  hipLaunchKernelGGL(scatter_reserve_kernel, dim3(NBLK), dim3(256), 0, stream,
                     row, col, gcur, ebuf, e, epb);
  hipLaunchKernelGGL(csr_kernel, dim3(nbuckets), dim3(256), 0, stream,
                     ebuf, gcur, offS, offE, srt, dinv, n);
  hipLaunchKernelGGL(prep_w_kernel, dim3(1), dim3(256), 0, stream,
                     W1, W2, w1t_hi, w1t_lo, w2t_hi, w2t_lo);
  hipLaunchKernelGGL(gemm1_mfma_kernel, dim3((n + 63) / 64), dim3(256), 0, stream,
                     x, w1t_hi, w1t_lo, dinv, xw1q, n, planeN);
  hipLaunchKernelGGL(gather1_plane_kernel, dim3(chunks * 4), dim3(256), 0, stream,
                     offS, offE, srt, dinv, xw1q, b1, hb, n, planeN);
  hipLaunchKernelGGL(gemm2_mfma_kernel, dim3((n + 63) / 64), dim3(256), 0, stream,
                     hb, w2t_hi, w2t_lo, dinv, hw2h, n, planeN);
  hipLaunchKernelGGL(gather2_plane_kernel, dim3(chunks * 2), dim3(256), 0, stream,
                     offS, offE, srt, dinv, hw2h, b2, out, n, planeN);
}

// Round 9
// 293.052 us; speedup vs baseline: 1.0768x; 1.0768x over previous
//
#include <hip/hip_runtime.h>

#define IN_C 128
#define HID_C 64
#define OUT_C 32
#define NBLK 512    // edge blocks for bucket partition
#define NBUCK 512   // buckets = node>>8 (391 used for n=100000)
#define CAP 5120    // fixed bucket capacity: mean 4096 + 16 sigma

typedef unsigned int uint;
typedef unsigned short ushort;
typedef __attribute__((ext_vector_type(8))) short bf16x8;
typedef __attribute__((ext_vector_type(4))) float f32x4;

__device__ __forceinline__ uint bf16pair(float a, float b) {
  uint ua = __float_as_uint(a), ub = __float_as_uint(b);
  ua = (ua + 0x7FFFu + ((ua >> 16) & 1u)) >> 16;
  ub = (ub + 0x7FFFu + ((ub >> 16) & 1u)) >> 16;
  return ua | (ub << 16);
}

__device__ __forceinline__ uint bf16one(float a) {
  uint u = __float_as_uint(a);
  return (u + 0x7FFFu + ((u >> 16) & 1u)) >> 16;
}

// Accumulate 8 bf16 feats (one dwordx4) into 8 f32 accumulators.
__device__ __forceinline__ void acc8(float* acc, uint4 q) {
  acc[0] += __uint_as_float(q.x << 16);
  acc[1] += __uint_as_float(q.x & 0xFFFF0000u);
  acc[2] += __uint_as_float(q.y << 16);
  acc[3] += __uint_as_float(q.y & 0xFFFF0000u);
  acc[4] += __uint_as_float(q.z << 16);
  acc[5] += __uint_as_float(q.z & 0xFFFF0000u);
  acc[6] += __uint_as_float(q.w << 16);
  acc[7] += __uint_as_float(q.w & 0xFFFF0000u);
}

// ---------- CSR build ----------

__global__ void __launch_bounds__(256) scatter_reserve_kernel(
    const int* __restrict__ row, const int* __restrict__ col,
    int* __restrict__ gcur, int* __restrict__ ebuf, int e, int epb) {
  __shared__ int hist[NBUCK];
  __shared__ int cur[NBUCK];
  int t = threadIdx.x, b = blockIdx.x;
  for (int i = t; i < NBUCK; i += 256) hist[i] = 0;
  __syncthreads();
  int s = b * epb, en = min(e, s + epb);
  for (int i = s + t; i < en; i += 256) atomicAdd(&hist[col[i] >> 8], 1);
  __syncthreads();
  for (int i = t; i < NBUCK; i += 256) {
    int h = hist[i];
    int base = h ? atomicAdd(&gcur[i], h) : 0;
    cur[i] = CAP * i + base;
  }
  __syncthreads();
  for (int i = s + t; i < en; i += 256) {
    int c = col[i], r = row[i];
    int bk = c >> 8;
    int p = atomicAdd(&cur[bk], 1);
    if (p < CAP * bk + CAP) ebuf[p] = r | ((c & 255) << 17);  // n < 2^17
  }
}

__global__ void __launch_bounds__(256) csr_kernel(const int* __restrict__ ebuf,
                                                  const int* __restrict__ gcur,
                                                  int* __restrict__ offS, int* __restrict__ offE,
                                                  int* __restrict__ srt, float* __restrict__ dinv,
                                                  int n) {
  __shared__ int cnt[256];
  __shared__ int base[256];
  int t = threadIdx.x, b = blockIdx.x;
  int es = b * CAP;
  int ec = min(gcur[b], CAP);
  cnt[t] = 0;
  __syncthreads();
  for (int i = t; i < ec; i += 256) atomicAdd(&cnt[(ebuf[es + i] >> 17) & 255], 1);
  __syncthreads();
  int v = cnt[t];
  base[t] = v;
  __syncthreads();
  for (int d = 1; d < 256; d <<= 1) {
    int a = (t >= d) ? base[t - d] : 0;
    __syncthreads();
    base[t] += a;
    __syncthreads();
  }
  int gstart = es + base[t] - v;
  int node = b * 256 + t;
  if (node < n) {
    offS[node] = gstart;
    offE[node] = gstart + v;
    dinv[node] = rsqrtf((float)(v + 1));
  }
  base[t] = gstart;  // repurpose as cursor
  __syncthreads();
  for (int i = t; i < ec; i += 256) {
    int pv = ebuf[es + i];
    int pos = atomicAdd(&base[(pv >> 17) & 255], 1);
    srt[pos] = pv & 0x1FFFF;
  }
}

// ---------- weight prep (bf16 hi/lo splits, transposed) ----------

__global__ void __launch_bounds__(256) prep_w_kernel(const float* __restrict__ W1,
                                                     const float* __restrict__ W2,
                                                     ushort* __restrict__ w1t_hi,
                                                     ushort* __restrict__ w1t_lo,
                                                     ushort* __restrict__ w2t_hi,
                                                     ushort* __restrict__ w2t_lo) {
  int t = threadIdx.x;
  for (int i = t; i < HID_C * IN_C; i += 256) {
    int c = i >> 7, k = i & 127;
    float v = W1[k * HID_C + c];
    uint h = bf16one(v);
    float lo = v - __uint_as_float(h << 16);
    w1t_hi[i] = (ushort)h;
    w1t_lo[i] = (ushort)bf16one(lo);
  }
  for (int i = t; i < OUT_C * HID_C; i += 256) {
    int c = i >> 6, k = i & 63;
    float v = W2[k * OUT_C + c];
    uint h = bf16one(v);
    float lo = v - __uint_as_float(h << 16);
    w2t_hi[i] = (ushort)h;
    w2t_lo[i] = (ushort)bf16one(lo);
  }
}

// ---------- gemm1 via split-bf16 MFMA -> quarter planes ----------
// xw1q[q][r][16] = bf16((x[r,:] @ W1)[:,q*16..] * dinv[r]).  64 rows/block.
#define APAD 136
__global__ void __launch_bounds__(256) gemm1_mfma_kernel(
    const float* __restrict__ x, const ushort* __restrict__ w1t_hi,
    const ushort* __restrict__ w1t_lo, const float* __restrict__ dinv,
    ushort* __restrict__ xw1q, int n, int planeN) {
  __shared__ ushort xs_hi[64 * APAD];
  __shared__ ushort xs_lo[64 * APAD];
  __shared__ float dinv_s[64];
  int t = threadIdx.x;
  int row0 = blockIdx.x * 64;
  if (t < 64) {
    int rr = row0 + t;
    dinv_s[t] = rr < n ? dinv[rr] : 0.f;
  }
  for (int task = t; task < 64 * 16; task += 256) {
    int r = task >> 4, kc = task & 15;
    int grow = row0 + r;
    uint4 hq = {0u, 0u, 0u, 0u}, lq = {0u, 0u, 0u, 0u};
    if (grow < n) {
      const float* xp = x + (size_t)grow * IN_C + kc * 8;
      float4 v0 = *(const float4*)xp;
      float4 v1 = *(const float4*)(xp + 4);
      float vv[8] = {v0.x, v0.y, v0.z, v0.w, v1.x, v1.y, v1.z, v1.w};
      uint hu[8];
      float lf[8];
#pragma unroll
      for (int i = 0; i < 8; ++i) {
        hu[i] = bf16one(vv[i]);
        lf[i] = vv[i] - __uint_as_float(hu[i] << 16);
      }
      hq = make_uint4(hu[0] | (hu[1] << 16), hu[2] | (hu[3] << 16),
                      hu[4] | (hu[5] << 16), hu[6] | (hu[7] << 16));
      lq = make_uint4(bf16pair(lf[0], lf[1]), bf16pair(lf[2], lf[3]),
                      bf16pair(lf[4], lf[5]), bf16pair(lf[6], lf[7]));
    }
    *(uint4*)(xs_hi + r * APAD + kc * 8) = hq;
    *(uint4*)(xs_lo + r * APAD + kc * 8) = lq;
  }
  __syncthreads();
  int wv = t >> 6, lane = t & 63, m = lane & 15, q = lane >> 4;
  f32x4 acc[4];
#pragma unroll
  for (int ct = 0; ct < 4; ++ct) acc[ct] = (f32x4){0.f, 0.f, 0.f, 0.f};
  const ushort* ah_p = xs_hi + (wv * 16 + m) * APAD + q * 8;
  const ushort* al_p = xs_lo + (wv * 16 + m) * APAD + q * 8;
#pragma unroll
  for (int kb = 0; kb < 4; ++kb) {
    bf16x8 ah = *(const bf16x8*)(ah_p + kb * 32);
    bf16x8 al = *(const bf16x8*)(al_p + kb * 32);
#pragma unroll
    for (int ct = 0; ct < 4; ++ct) {
      const ushort* bp = w1t_hi + (ct * 16 + m) * IN_C + kb * 32 + q * 8;
      bf16x8 bh = *(const bf16x8*)bp;
      bf16x8 bl = *(const bf16x8*)(bp + (size_t)(w1t_lo - w1t_hi));
      acc[ct] = __builtin_amdgcn_mfma_f32_16x16x32_bf16(ah, bh, acc[ct], 0, 0, 0);
      acc[ct] = __builtin_amdgcn_mfma_f32_16x16x32_bf16(al, bh, acc[ct], 0, 0, 0);
      acc[ct] = __builtin_amdgcn_mfma_f32_16x16x32_bf16(ah, bl, acc[ct], 0, 0, 0);
    }
  }
#pragma unroll
  for (int ct = 0; ct < 4; ++ct) {
#pragma unroll
    for (int rg = 0; rg < 4; ++rg) {
      int lr = wv * 16 + q * 4 + rg;
      int grow = row0 + lr;
      if (grow < n)
        xw1q[(size_t)ct * planeN + (size_t)grow * 16 + m] =
            (ushort)bf16one(acc[ct][rg] * dinv_s[lr]);
    }
  }
}

// ---------- plane gathers (2-lane groups, dwordx4 loads) ----------

// gather1: plane = bid&3 (XCD-pinned, 3.2 MB plane); 128 nodes/block,
// 2-lane group per node, lane = 16 B half of the 32 B plane row.
__global__ void __launch_bounds__(256) gather1_q_kernel(
    const int* __restrict__ offS, const int* __restrict__ offE, const int* __restrict__ srt,
    const float* __restrict__ dinv, const ushort* __restrict__ xw1q,
    const float* __restrict__ b1, ushort* __restrict__ hbq, int n, int planeN) {
  int t = threadIdx.x, bid = blockIdx.x;
  int pq = bid & 3, chunk = bid >> 2;
  int g = t >> 1, fl = t & 1;
  int c = chunk * 128 + g;
  if (c >= n) return;
  const uint4* tbl = (const uint4*)(xw1q + (size_t)pq * planeN);
  int js = offS[c], je = offE[c];
  float a[8] = {0.f, 0.f, 0.f, 0.f, 0.f, 0.f, 0.f, 0.f};
  float b[8] = {0.f, 0.f, 0.f, 0.f, 0.f, 0.f, 0.f, 0.f};
  int j = js;
  for (; j + 3 < je; j += 4) {
    int r0 = __builtin_nontemporal_load(srt + j);
    int r1 = __builtin_nontemporal_load(srt + j + 1);
    int r2 = __builtin_nontemporal_load(srt + j + 2);
    int r3 = __builtin_nontemporal_load(srt + j + 3);
    uint4 q0 = tbl[(size_t)r0 * 2 + fl];
    uint4 q1 = tbl[(size_t)r1 * 2 + fl];
    uint4 q2 = tbl[(size_t)r2 * 2 + fl];
    uint4 q3 = tbl[(size_t)r3 * 2 + fl];
    acc8(a, q0); acc8(b, q1); acc8(a, q2); acc8(b, q3);
  }
  for (; j < je; ++j) {
    int r = __builtin_nontemporal_load(srt + j);
    acc8(a, tbl[(size_t)r * 2 + fl]);
  }
  acc8(a, tbl[(size_t)c * 2 + fl]);  // self loop
  float dv = dinv[c];
  const float4* bv = (const float4*)b1;
  float4 b0 = bv[pq * 4 + fl * 2], b1v = bv[pq * 4 + fl * 2 + 1];
  float h0 = (a[0] + b[0]) * dv + b0.x;
  float h1 = (a[1] + b[1]) * dv + b0.y;
  float h2 = (a[2] + b[2]) * dv + b0.z;
  float h3 = (a[3] + b[3]) * dv + b0.w;
  float h4 = (a[4] + b[4]) * dv + b1v.x;
  float h5 = (a[5] + b[5]) * dv + b1v.y;
  float h6 = (a[6] + b[6]) * dv + b1v.z;
  float h7 = (a[7] + b[7]) * dv + b1v.w;
  h0 = h0 > 0.f ? h0 : 0.f; h1 = h1 > 0.f ? h1 : 0.f;
  h2 = h2 > 0.f ? h2 : 0.f; h3 = h3 > 0.f ? h3 : 0.f;
  h4 = h4 > 0.f ? h4 : 0.f; h5 = h5 > 0.f ? h5 : 0.f;
  h6 = h6 > 0.f ? h6 : 0.f; h7 = h7 > 0.f ? h7 : 0.f;
  uint4 o = make_uint4(bf16pair(h0, h1), bf16pair(h2, h3),
                       bf16pair(h4, h5), bf16pair(h6, h7));
  *(uint4*)(hbq + (size_t)pq * planeN + (size_t)c * 16 + fl * 8) = o;
}

// gemm2 via MFMA: hw2h[h][r][16] = bf16((h[r,:] @ W2)[:,h*16..] * dinv[r]).
// A read from hbq plane layout (feats q*8 -> plane q>>1, offset (q&1)*8).
__global__ void __launch_bounds__(256) gemm2_mfma_kernel(
    const ushort* __restrict__ hbq, const ushort* __restrict__ w2t_hi,
    const ushort* __restrict__ w2t_lo, const float* __restrict__ dinv,
    ushort* __restrict__ hw2h, int n, int planeN) {
  int t = threadIdx.x;
  int wv = t >> 6, lane = t & 63, m = lane & 15, q = lane >> 4;
  int row0 = blockIdx.x * 64 + wv * 16;
  int arow = min(row0 + m, n - 1);
  const ushort* abase = hbq + (size_t)arow * 16 + (q & 1) * 8;
  bf16x8 a0 = *(const bf16x8*)(abase + (size_t)(q >> 1) * planeN);
  bf16x8 a1 = *(const bf16x8*)(abase + (size_t)(2 + (q >> 1)) * planeN);
  f32x4 acc[2];
  acc[0] = (f32x4){0.f, 0.f, 0.f, 0.f};
  acc[1] = (f32x4){0.f, 0.f, 0.f, 0.f};
#pragma unroll
  for (int ct = 0; ct < 2; ++ct) {
    const ushort* bp = w2t_hi + (ct * 16 + m) * HID_C + q * 8;
    const ushort* blp = w2t_lo + (ct * 16 + m) * HID_C + q * 8;
    bf16x8 bh0 = *(const bf16x8*)bp;
    bf16x8 bh1 = *(const bf16x8*)(bp + 32);
    bf16x8 bl0 = *(const bf16x8*)blp;
    bf16x8 bl1 = *(const bf16x8*)(blp + 32);
    acc[ct] = __builtin_amdgcn_mfma_f32_16x16x32_bf16(a0, bh0, acc[ct], 0, 0, 0);
    acc[ct] = __builtin_amdgcn_mfma_f32_16x16x32_bf16(a1, bh1, acc[ct], 0, 0, 0);
    acc[ct] = __builtin_amdgcn_mfma_f32_16x16x32_bf16(a0, bl0, acc[ct], 0, 0, 0);
    acc[ct] = __builtin_amdgcn_mfma_f32_16x16x32_bf16(a1, bl1, acc[ct], 0, 0, 0);
  }
#pragma unroll
  for (int ct = 0; ct < 2; ++ct) {
#pragma unroll
    for (int rg = 0; rg < 4; ++rg) {
      int node = row0 + q * 4 + rg;
      if (node < n)
        hw2h[(size_t)ct * planeN + (size_t)node * 16 + m] =
            (ushort)bf16one(acc[ct][rg] * dinv[node]);
    }
  }
}

// gather2: plane = bid&1 (3.2 MB plane); 128 nodes/block, 2-lane group,
// lane = 16 B half of the 32 B plane row. Writes final f32 output.
__global__ void __launch_bounds__(256) gather2_h_kernel(
    const int* __restrict__ offS, const int* __restrict__ offE, const int* __restrict__ srt,
    const float* __restrict__ dinv, const ushort* __restrict__ hw2h,
    const float* __restrict__ b2, float* __restrict__ out, int n, int planeN) {
  int t = threadIdx.x, bid = blockIdx.x;
  int ph = bid & 1, chunk = bid >> 1;
  int g = t >> 1, fl = t & 1;
  int c = chunk * 128 + g;
  if (c >= n) return;
  const uint4* tbl = (const uint4*)(hw2h + (size_t)ph * planeN);
  int js = offS[c], je = offE[c];
  float a[8] = {0.f, 0.f, 0.f, 0.f, 0.f, 0.f, 0.f, 0.f};
  float b[8] = {0.f, 0.f, 0.f, 0.f, 0.f, 0.f, 0.f, 0.f};
  int j = js;
  for (; j + 3 < je; j += 4) {
    int r0 = __builtin_nontemporal_load(srt + j);
    int r1 = __builtin_nontemporal_load(srt + j + 1);
    int r2 = __builtin_nontemporal_load(srt + j + 2);
    int r3 = __builtin_nontemporal_load(srt + j + 3);
    uint4 q0 = tbl[(size_t)r0 * 2 + fl];
    uint4 q1 = tbl[(size_t)r1 * 2 + fl];
    uint4 q2 = tbl[(size_t)r2 * 2 + fl];
    uint4 q3 = tbl[(size_t)r3 * 2 + fl];
    acc8(a, q0); acc8(b, q1); acc8(a, q2); acc8(b, q3);
  }
  for (; j < je; ++j) {
    int r = __builtin_nontemporal_load(srt + j);
    acc8(a, tbl[(size_t)r * 2 + fl]);
  }
  acc8(a, tbl[(size_t)c * 2 + fl]);  // self loop
  float dv = dinv[c];
  const float4* bv = (const float4*)b2;
  float4 b0 = bv[ph * 4 + fl * 2], b1v = bv[ph * 4 + fl * 2 + 1];
  float4 olo = {(a[0] + b[0]) * dv + b0.x, (a[1] + b[1]) * dv + b0.y,
                (a[2] + b[2]) * dv + b0.z, (a[3] + b[3]) * dv + b0.w};
  float4 ohi = {(a[4] + b[4]) * dv + b1v.x, (a[5] + b[5]) * dv + b1v.y,
                (a[6] + b[6]) * dv + b1v.z, (a[7] + b[7]) * dv + b1v.w};
  float* op = out + (size_t)c * OUT_C + ph * 16 + fl * 8;
  *(float4*)op = olo;
  *(float4*)(op + 4) = ohi;
}

extern "C" void kernel_launch(void* const* d_in, const int* in_sizes, int n_in,
                              void* d_out, int out_size, void* d_ws, size_t ws_size,
                              hipStream_t stream) {
  const float* x  = (const float*)d_in[0];
  const int*   ei = (const int*)d_in[1];
  const float* W1 = (const float*)d_in[2];
  const float* b1 = (const float*)d_in[3];
  const float* W2 = (const float*)d_in[4];
  const float* b2 = (const float*)d_in[5];
  float* out = (float*)d_out;

  int n = in_sizes[0] / IN_C;  // 100000
  int e = in_sizes[1] / 2;     // 1600000
  const int* row = ei;         // sources
  const int* col = ei + e;     // targets
  int planeN = n * 16;         // bf16 elems per feature plane

  // workspace (ebuf aliases xw1q — ebuf dead before gemm1 runs, stream-ordered)
  float* dinv = (float*)d_ws;                          // n
  int*   offS = (int*)(dinv + n);                      // n
  int*   offE = offS + n;                              // n
  int*   gcur = offE + n;                              // NBUCK
  int*   srt  = gcur + NBUCK;                          // NBUCK*CAP
  ushort* xw1q = (ushort*)(srt + (size_t)NBUCK * CAP); // 4 planes x n*16
  int*   ebuf = (int*)xw1q;                            // NBUCK*CAP ints (10.5MB <= 12.8MB)
  ushort* hbq  = xw1q + (size_t)n * HID_C;             // 4 planes x n*16
  ushort* hw2h = hbq + (size_t)n * HID_C;              // 2 planes x n*16
  ushort* w1t_hi = hw2h + (size_t)n * OUT_C;           // 64*128
  ushort* w1t_lo = w1t_hi + HID_C * IN_C;              // 64*128
  ushort* w2t_hi = w1t_lo + HID_C * IN_C;              // 32*64
  ushort* w2t_lo = w2t_hi + OUT_C * HID_C;             // 32*64

  int epb = (e + NBLK - 1) / NBLK;                     // 3125
  int nbuckets = (n + 255) / 256;                      // 391
  int cpp = (n + 127) / 128;                           // 782 chunks (128 nodes each)

  hipMemsetAsync(gcur, 0, NBUCK * sizeof(int), stream);
  hipLaunchKernelGGL(scatter_reserve_kernel, dim3(NBLK), dim3(256), 0, stream,
                     row, col, gcur, ebuf, e, epb);
  hipLaunchKernelGGL(csr_kernel, dim3(nbuckets), dim3(256), 0, stream,
                     ebuf, gcur, offS, offE, srt, dinv, n);
  hipLaunchKernelGGL(prep_w_kernel, dim3(1), dim3(256), 0, stream,
                     W1, W2, w1t_hi, w1t_lo, w2t_hi, w2t_lo);
  hipLaunchKernelGGL(gemm1_mfma_kernel, dim3((n + 63) / 64), dim3(256), 0, stream,
                     x, w1t_hi, w1t_lo, dinv, xw1q, n, planeN);
  hipLaunchKernelGGL(gather1_q_kernel, dim3(cpp * 4), dim3(256), 0, stream,
                     offS, offE, srt, dinv, xw1q, b1, hbq, n, planeN);
  hipLaunchKernelGGL(gemm2_mfma_kernel, dim3((n + 63) / 64), dim3(256), 0, stream,
                     hbq, w2t_hi, w2t_lo, dinv, hw2h, n, planeN);
  hipLaunchKernelGGL(gather2_h_kernel, dim3(cpp * 2), dim3(256), 0, stream,
                     offS, offE, srt, dinv, hw2h, b2, out, n, planeN);
}